// Round 10
// baseline (402.382 us; speedup 1.0000x reference)
//
#include <hip/hip_runtime.h>
#include <math.h>

#define NT 128          // threads per workgroup (2 waves)
#define NWG 4           // workgroups per batch element
#define BATCH 64
#define QDIM 4096       // 2^12 amps per batch state
#define LOCAL_AMPS 1024 // per workgroup

typedef float v2f __attribute__((ext_vector_type(2)));
using F2 = float2;

__device__ __forceinline__ v2f mkv(float x, float y) { v2f r; r.x = x; r.y = y; return r; }

// ---- packed complex ops (VOP3P dual-FP32) ----
__device__ __forceinline__ v2f cfma(v2f m, v2f a, v2f acc) {   // acc + m*a (complex)
    v2f r;
    asm("v_pk_fma_f32 %0, %1, %2, %3 op_sel:[0,0,0] op_sel_hi:[0,1,1]\n\t"
        "v_pk_fma_f32 %0, %1, %2, %0 op_sel:[1,1,0] op_sel_hi:[1,0,1] neg_lo:[1,0,0]"
        : "=&v"(r) : "v"(m), "v"(a), "v"(acc));
    return r;
}
__device__ __forceinline__ v2f cmulp(v2f m, v2f a) {           // m*a (complex)
    v2f r;
    asm("v_pk_mul_f32 %0, %1, %2 op_sel:[0,0] op_sel_hi:[0,1]\n\t"
        "v_pk_fma_f32 %0, %1, %2, %0 op_sel:[1,1,0] op_sel_hi:[1,0,1] neg_lo:[1,0,0]"
        : "=&v"(r) : "v"(m), "v"(a));
    return r;
}

// ---- scalar complex helpers for the table build (once per wg) ----
__device__ __forceinline__ F2 cadd(F2 p, F2 q) { return make_float2(p.x + q.x, p.y + q.y); }
__device__ __forceinline__ F2 cmul(F2 p, F2 q) {
    return make_float2(p.x * q.x - p.y * q.y, p.x * q.y + p.y * q.x);
}
struct M2 { F2 a, b, c, d; };
__device__ __forceinline__ M2 mmul(M2 A, M2 B) {
    M2 R;
    R.a = cadd(cmul(A.a, B.a), cmul(A.b, B.c));
    R.b = cadd(cmul(A.a, B.b), cmul(A.b, B.d));
    R.c = cadd(cmul(A.c, B.a), cmul(A.d, B.c));
    R.d = cadd(cmul(A.c, B.b), cmul(A.d, B.d));
    return R;
}
__device__ __forceinline__ M2 mrx(float t) {
    float s, c; sincosf(0.5f * t, &s, &c);
    return { make_float2(c, 0), make_float2(0, -s), make_float2(0, -s), make_float2(c, 0) };
}
__device__ __forceinline__ M2 mry(float t) {
    float s, c; sincosf(0.5f * t, &s, &c);
    return { make_float2(c, 0), make_float2(-s, 0), make_float2(s, 0), make_float2(c, 0) };
}
__device__ __forceinline__ M2 mrz(float t) {
    float s, c; sincosf(0.5f * t, &s, &c);
    return { make_float2(c, -s), make_float2(0, 0), make_float2(0, 0), make_float2(c, s) };
}
#define RSQ2 0.70710678118654752f
__device__ __forceinline__ M2 mH() {
    return { make_float2(RSQ2, 0), make_float2(RSQ2, 0), make_float2(RSQ2, 0), make_float2(-RSQ2, 0) };
}
__device__ __forceinline__ M2 mW() {   // W = H*S; W† Z W = -Y => YY = W†⊗W† ZZ W⊗W
    return { make_float2(RSQ2, 0), make_float2(0, RSQ2), make_float2(RSQ2, 0), make_float2(0, -RSQ2) };
}
__device__ __forceinline__ M2 mWd() {
    return { make_float2(RSQ2, 0), make_float2(RSQ2, 0), make_float2(0, -RSQ2), make_float2(0, RSQ2) };
}

// ================= layouts =================
// wg identity: bat = blockIdx & 63, g = blockIdx >> 6 (2 bits).  tid = w*64 + l (w: 1 bit).
// L0: k = j | l<<3 | w<<9 | g<<10     L1: k = (l&7) | j<<3 | (l>>3)<<6 | w<<9 | g<<10
// L2: k = l | j<<6 | w<<9 | g<<10     L3: k = j<<9 | T,  T = g<<7 | w<<6 | l
// L0<->L1<->L2 trips are intra-wave (LDS, no barrier).  L2<->L3 and CNOT are global exchanges.

// ---- intra-wave trips (wave-private 512-v2f region wb, NO barrier) ----
template<int TYPE>   // TYPE 0: <0,1>/<1,0>   TYPE 1: <1,2>/<2,1>
__device__ __forceinline__ void itrip(v2f* amp, int l, v2f* wb) {
#pragma unroll
    for (int j = 0; j < 8; ++j) wb[j * 64 + (l ^ ((9 * j) & 63))] = amp[j];
    asm volatile("" ::: "memory");   // compiler fence; DS pipe is in-order per wave
#pragma unroll
    for (int j = 0; j < 8; ++j) {
        int jo, lo;
        if (TYPE == 0) { jo = l & 7;        lo = j | (l & 56); }
        else           { jo = (l >> 3) & 7; lo = (l & 7) | (j << 3); }
        amp[j] = wb[jo * 64 + (lo ^ ((9 * jo) & 63))];
    }
}

// ---- 4-way inter-workgroup sync (device-scope; bounded spin) ----
__device__ __forceinline__ void wg_sync4(unsigned* c, int tid) {
    __threadfence();            // release: make prior global writes device-visible
    __syncthreads();
    if (tid == 0) {
        __hip_atomic_fetch_add(c, 1u, __ATOMIC_ACQ_REL, __HIP_MEMORY_SCOPE_AGENT);
        int guard = 0;
        while (__hip_atomic_load(c, __ATOMIC_ACQUIRE, __HIP_MEMORY_SCOPE_AGENT) < 4u
               && guard < (1 << 24)) { ++guard; __builtin_amdgcn_s_sleep(1); }
    }
    __syncthreads();
    __threadfence();            // acquire reinforcement before reading partners' data
}

// ---- gate-matrix trio: 12 v2f in registers, loaded via 6x ds_read_b128 ----
struct Trio { v2f m[12]; };
__device__ __forceinline__ Trio load_trio(const float4 (*g4)[2]) {
    Trio t;
#pragma unroll
    for (int k = 0; k < 3; ++k) {
        float4 a = g4[k][0], b = g4[k][1];
        t.m[k * 4 + 0] = mkv(a.x, a.y); t.m[k * 4 + 1] = mkv(a.z, a.w);
        t.m[k * 4 + 2] = mkv(b.x, b.y); t.m[k * 4 + 3] = mkv(b.z, b.w);
    }
    return t;
}

template<int JB>
__device__ __forceinline__ void g1_reg(v2f* amp, const v2f* g) {
    const int m = 1 << JB;
    v2f m00 = g[0], m01 = g[1], m10 = g[2], m11 = g[3];
#pragma unroll
    for (int j = 0; j < 8; ++j)
        if (!(j & m)) {
            v2f a = amp[j], b = amp[j | m];
            amp[j]     = cfma(m01, b, cmulp(m00, a));
            amp[j | m] = cfma(m11, b, cmulp(m10, a));
        }
}
__device__ __forceinline__ void apply_trio(v2f* amp, const Trio& t) {
    g1_reg<0>(amp, t.m + 0);  g1_reg<1>(amp, t.m + 4);  g1_reg<2>(amp, t.m + 8);
}

// ---- fused diagonal Ising phase (all 12 ring edges) in L3: k = j<<9 | T ----
__device__ __forceinline__ void diag_L3(v2f* amp, const float* zh, int T) {
    float phi0 = 0.f;
#pragma unroll
    for (int e = 3; e <= 10; ++e) {   // edges entirely in T bits: thread-constant
        int hi = 11 - e, lo = 10 - e;
        phi0 += (((T >> hi) ^ (T >> lo)) & 1) ? zh[e] : -zh[e];
    }
    float z0 = zh[0], z1 = zh[1], z2 = zh[2], z11 = zh[11];
    int t8 = (T >> 8) & 1, t0 = T & 1;
#pragma unroll
    for (int j = 0; j < 8; ++j) {
        int j0 = j & 1, j1 = (j >> 1) & 1, j2 = (j >> 2) & 1;
        float phi = phi0
            + ((j2 ^ j1) ? z0 : -z0)       // (11,10)
            + ((j1 ^ j0) ? z1 : -z1)       // (10,9)
            + ((j0 ^ t8) ? z2 : -z2)       // (9,8)
            + ((j2 ^ t0) ? z11 : -z11);    // (11,0)
        float sp, cp;
        __sincosf(phi, &sp, &cp);
        amp[j] = cmulp(mkv(cp, sp), amp[j]);
    }
}

// ---- composed CNOT-ring source index ----
__device__ __forceinline__ int cnot_src(int k) {
#pragma unroll
    for (int e = 11; e >= 0; --e) {
        int hi = (e < 11) ? 11 - e : 11, lo = (e < 11) ? 10 - e : 0;
        if ((k >> hi) & 1) k ^= (1 << lo);
    }
    return k;
}

__global__ __launch_bounds__(NT) void qsim_kernel(
    const float* __restrict__ data,       // [64,12]
    const float* __restrict__ enc_scale,  // [12,3]
    const float* __restrict__ enc_bias,   // [12,3]
    const float* __restrict__ eta,        // [1,3]
    const float* __restrict__ ew_zz,      // [1,12]
    const float* __restrict__ ew_xx,      // [1,12]
    const float* __restrict__ ew_yy,      // [1,12]
    const float* __restrict__ nb_z,       // [1,12]
    const float* __restrict__ nb_x,       // [1,12]
    const float* __restrict__ nb_y,       // [1,12]
    const float* __restrict__ trots,      // [1,3,12,3]
    v2f*   __restrict__ xb,               // exchange buffers: 9 regions x 64 batches x 4096
    unsigned* __restrict__ cnt,           // 9*64 exchange counters (zeroed)
    unsigned* __restrict__ fin,           // 64 final counters (zeroed)
    float* __restrict__ accb,             // 64*12 accumulators (zeroed)
    float* __restrict__ out)              // [64,12]
{
    __shared__ v2f ibuf[2 * 512];         // intra-wave trip buffer (512 v2f per wave)
    __shared__ float4 g1q4[72][2];        // fused 1q matrices, 32 B each
    __shared__ float zhalf[3][12];
    __shared__ float red[2][12];
    __shared__ int lastflag;

    const int tid = threadIdx.x;
    const int l = tid & 63, w = tid >> 6;
    const int bat = blockIdx.x & 63;
    const int g   = blockIdx.x >> 6;
    v2f* wb = &ibuf[w * 512];

    // ---- fused gate tables (Ising basis changes folded into neighbors) ----
    if (tid < 36) {                      // encoding: b = tid/12, q = tid%12
        int b = tid / 12, q = tid % 12;
        float x  = data[bat * 12 + q];
        float ax = enc_scale[q * 3 + 0] * x + enc_bias[q * 3 + 0];
        float ay = enc_scale[q * 3 + 1] * x + enc_bias[q * 3 + 1];
        float az = enc_scale[q * 3 + 2] * x + enc_bias[q * 3 + 2];
        M2 M;
        if (b == 0)      M = mmul(mrz(az), mmul(mry(ay), mrx(ax)));   // ZZ: no basis change
        else if (b == 1) M = mmul(mH(), mmul(mry(ay), mrx(ax)));      // XX: H after enc
        else             M = mmul(mW(), mmul(mrz(az), mry(ay)));      // YY: W after enc
        g1q4[tid][0] = make_float4(M.a.x, M.a.y, M.b.x, M.b.y);
        g1q4[tid][1] = make_float4(M.c.x, M.c.y, M.d.x, M.d.y);
    } else if (tid < 72) {               // bias + trainables (+ closing basis change first)
        int i = tid - 36, b = i / 12, q = i % 12;
        float nb = (b == 0) ? nb_z[q] : (b == 1) ? nb_x[q] : nb_y[q];
        M2 M0 = (b == 0) ? mrz(nb) : (b == 1) ? mrx(nb) : mry(nb);
        float t0 = trots[(b * 12 + q) * 3 + 0];
        float t1 = trots[(b * 12 + q) * 3 + 1];
        float t2 = trots[(b * 12 + q) * 3 + 2];
        M2 M = mmul(mrz(t2), mmul(mry(t1), mmul(mrx(t0), M0)));
        if (b == 1)      M = mmul(M, mH());
        else if (b == 2) M = mmul(M, mWd());
        g1q4[tid][0] = make_float4(M.a.x, M.a.y, M.b.x, M.b.y);
        g1q4[tid][1] = make_float4(M.c.x, M.c.y, M.d.x, M.d.y);
    } else if (tid < 108) {              // diagonal half-angles per block/edge
        int i = tid - 72, b = i / 12, e = i % 12;
        const float* ew = (b == 0) ? ew_zz : (b == 1) ? ew_xx : ew_yy;
        zhalf[b][e] = 0.5f * eta[b] * ew[e];
    }
    __syncthreads();

    // ---- state: L0, this wg holds k = j | l<<3 | w<<9 | g<<10 ----
    v2f amp[8];
#pragma unroll
    for (int j = 0; j < 8; ++j) amp[j] = mkv(0.f, 0.f);
    if (g == 0 && tid == 0) amp[0].x = 1.f;

    const int T = (g << 7) | (w << 6) | l;            // L3 low-bit coordinate
    const int K0 = (g << 10) | (w << 9) | (l << 3);   // L0 canonical base (j in low bits)
    int ksrc[8];
#pragma unroll
    for (int j = 0; j < 8; ++j) ksrc[j] = cnot_src(K0 | j);

    for (int blk = 0; blk < 3; ++blk) {
        const float4(*Ge)[2] = &g1q4[blk * 12];
        const float4(*Gb)[2] = &g1q4[36 + blk * 12];
        v2f* x1 = xb + ((size_t)((blk * 3 + 0) * BATCH + bat) << 12);
        v2f* x2 = xb + ((size_t)((blk * 3 + 1) * BATCH + bat) << 12);
        v2f* x3 = xb + ((size_t)((blk * 3 + 2) * BATCH + bat) << 12);

        // ---- encoding: L0 -> L1 -> L2 (intra-wave), pipelined trio loads ----
        Trio tA = load_trio(Ge + 0);
        Trio tB = load_trio(Ge + 3);
        apply_trio(amp, tA);
        itrip<0>(amp, l, wb);
        tA = load_trio(Ge + 6);
        apply_trio(amp, tB);
        itrip<1>(amp, l, wb);
        tB = load_trio(Ge + 9);
        apply_trio(amp, tA);

        // ---- exchange E1: L2 -> L3 (global, 4-way sync) ----
#pragma unroll
        for (int j = 0; j < 8; ++j) x1[(g << 10) | (w << 9) | (j << 6) | l] = amp[j];
        wg_sync4(&cnt[(blk * 3 + 0) * BATCH + bat], tid);
#pragma unroll
        for (int j = 0; j < 8; ++j) amp[j] = x1[(j << 9) | T];

        tA = load_trio(Gb + 9);
        apply_trio(amp, tB);          // enc gates q9-11
        diag_L3(amp, zhalf[blk], T);  // fused Ising diagonal
        apply_trio(amp, tA);          // bias gates q9-11

        // ---- exchange E2: L3 -> L2 (global, 4-way sync) ----
#pragma unroll
        for (int j = 0; j < 8; ++j) x2[(j << 9) | T] = amp[j];
        wg_sync4(&cnt[(blk * 3 + 1) * BATCH + bat], tid);
#pragma unroll
        for (int j = 0; j < 8; ++j) amp[j] = x2[(g << 10) | (w << 9) | (j << 6) | l];

        // ---- bias: L2 -> L1 -> L0 (intra-wave) ----
        tA = load_trio(Gb + 6);
        tB = load_trio(Gb + 3);
        apply_trio(amp, tA);
        itrip<1>(amp, l, wb);
        tA = load_trio(Gb + 0);
        apply_trio(amp, tB);
        itrip<0>(amp, l, wb);
        apply_trio(amp, tA);

        // ---- exchange E3: fused CNOT-ring permutation (global gather) ----
        {
            float4* dst = reinterpret_cast<float4*>(x3 + K0);
#pragma unroll
            for (int p = 0; p < 4; ++p)
                dst[p] = make_float4(amp[2 * p].x, amp[2 * p].y, amp[2 * p + 1].x, amp[2 * p + 1].y);
        }
        wg_sync4(&cnt[(blk * 3 + 2) * BATCH + bat], tid);
#pragma unroll
        for (int j = 0; j < 8; ++j) amp[j] = x3[ksrc[j]];
    }

    // ---- Pauli-Z expectations: per-wg partials + device accumulation ----
    float pr[8];
#pragma unroll
    for (int j = 0; j < 8; ++j) pr[j] = amp[j].x * amp[j].x + amp[j].y * amp[j].y;
    float psum = 0.f;
#pragma unroll
    for (int j = 0; j < 8; ++j) psum += pr[j];

    float acc[12];
#pragma unroll
    for (int i = 0; i < 9; ++i)
        acc[i] = ((T >> (8 - i)) & 1) ? -psum : psum;
#pragma unroll
    for (int i = 9; i < 12; ++i) {
        float s = 0.f;
        int bit = 11 - i;
#pragma unroll
        for (int j = 0; j < 8; ++j)
            s += ((j >> bit) & 1) ? -pr[j] : pr[j];
        acc[i] = s;
    }
#pragma unroll
    for (int off = 32; off > 0; off >>= 1)
#pragma unroll
        for (int i = 0; i < 12; ++i)
            acc[i] += __shfl_down(acc[i], off, 64);
    if (l == 0)
#pragma unroll
        for (int i = 0; i < 12; ++i) red[w][i] = acc[i];
    __syncthreads();
    if (tid < 12)
        atomicAdd(&accb[bat * 12 + tid], red[0][tid] + red[1][tid]);
    __threadfence();
    __syncthreads();
    if (tid == 0) {
        unsigned old = __hip_atomic_fetch_add(&fin[bat], 1u, __ATOMIC_ACQ_REL, __HIP_MEMORY_SCOPE_AGENT);
        lastflag = (int)old;
    }
    __syncthreads();
    if (lastflag == 3) {                 // last-arriving wg writes the output
        __threadfence();
        if (tid < 12)
            out[bat * 12 + tid] =
                __hip_atomic_load(&accb[bat * 12 + tid], __ATOMIC_RELAXED, __HIP_MEMORY_SCOPE_AGENT);
    }
}

extern "C" void kernel_launch(void* const* d_in, const int* in_sizes, int n_in,
                              void* d_out, int out_size, void* d_ws, size_t ws_size,
                              hipStream_t stream) {
    const float* data      = (const float*)d_in[0];
    const float* enc_scale = (const float*)d_in[1];
    const float* enc_bias  = (const float*)d_in[2];
    const float* eta       = (const float*)d_in[3];
    const float* ew_zz     = (const float*)d_in[4];
    const float* ew_xx     = (const float*)d_in[5];
    const float* ew_yy     = (const float*)d_in[6];
    const float* nb_z      = (const float*)d_in[7];
    const float* nb_x      = (const float*)d_in[8];
    const float* nb_y      = (const float*)d_in[9];
    const float* trots     = (const float*)d_in[10];
    float* out = (float*)d_out;

    // workspace layout: 9 exchange regions (64 batches x 4096 v2f), then counters/accum
    const size_t XB_BYTES = (size_t)9 * BATCH * QDIM * sizeof(float) * 2;
    v2f*      xb   = (v2f*)d_ws;
    unsigned* cnt  = (unsigned*)((char*)d_ws + XB_BYTES);     // 9*64
    unsigned* fin  = cnt + 9 * BATCH;                         // 64
    float*    accb = (float*)(fin + BATCH);                   // 64*12
    const size_t ZERO_BYTES = (9 * BATCH + BATCH) * sizeof(unsigned) + BATCH * 12 * sizeof(float);

    hipMemsetAsync(cnt, 0, ZERO_BYTES, stream);
    qsim_kernel<<<BATCH * NWG, NT, 0, stream>>>(data, enc_scale, enc_bias, eta,
                                                ew_zz, ew_xx, ew_yy,
                                                nb_z, nb_x, nb_y, trots,
                                                xb, cnt, fin, accb, out);
}

// Round 11
// 91.125 us; speedup vs baseline: 4.4157x; 4.4157x over previous
//
#include <hip/hip_runtime.h>
#include <math.h>

#define NT 512
#define QDIM 4096   // 2^12

typedef float v2f __attribute__((ext_vector_type(2)));
using F2 = float2;

__device__ __forceinline__ v2f mkv(float x, float y) { v2f r; r.x = x; r.y = y; return r; }

// ---- packed complex ops (VOP3P dual-FP32) ----
__device__ __forceinline__ v2f cfma(v2f m, v2f a, v2f acc) {   // acc + m*a (complex)
    v2f r;
    asm("v_pk_fma_f32 %0, %1, %2, %3 op_sel:[0,0,0] op_sel_hi:[0,1,1]\n\t"
        "v_pk_fma_f32 %0, %1, %2, %0 op_sel:[1,1,0] op_sel_hi:[1,0,1] neg_lo:[1,0,0]"
        : "=&v"(r) : "v"(m), "v"(a), "v"(acc));
    return r;
}
__device__ __forceinline__ v2f cmulp(v2f m, v2f a) {           // m*a (complex)
    v2f r;
    asm("v_pk_mul_f32 %0, %1, %2 op_sel:[0,0] op_sel_hi:[0,1]\n\t"
        "v_pk_fma_f32 %0, %1, %2, %0 op_sel:[1,1,0] op_sel_hi:[1,0,1] neg_lo:[1,0,0]"
        : "=&v"(r) : "v"(m), "v"(a));
    return r;
}

// ---- scalar complex helpers for the table build (once per block) ----
__device__ __forceinline__ F2 cadd(F2 p, F2 q) { return make_float2(p.x + q.x, p.y + q.y); }
__device__ __forceinline__ F2 cmul(F2 p, F2 q) {
    return make_float2(p.x * q.x - p.y * q.y, p.x * q.y + p.y * q.x);
}
struct M2 { F2 a, b, c, d; };
__device__ __forceinline__ M2 mmul(M2 A, M2 B) {
    M2 R;
    R.a = cadd(cmul(A.a, B.a), cmul(A.b, B.c));
    R.b = cadd(cmul(A.a, B.b), cmul(A.b, B.d));
    R.c = cadd(cmul(A.c, B.a), cmul(A.d, B.c));
    R.d = cadd(cmul(A.c, B.b), cmul(A.d, B.d));
    return R;
}
__device__ __forceinline__ M2 mrx(float t) {
    float s, c; sincosf(0.5f * t, &s, &c);
    return { make_float2(c, 0), make_float2(0, -s), make_float2(0, -s), make_float2(c, 0) };
}
__device__ __forceinline__ M2 mry(float t) {
    float s, c; sincosf(0.5f * t, &s, &c);
    return { make_float2(c, 0), make_float2(-s, 0), make_float2(s, 0), make_float2(c, 0) };
}
__device__ __forceinline__ M2 mrz(float t) {
    float s, c; sincosf(0.5f * t, &s, &c);
    return { make_float2(c, -s), make_float2(0, 0), make_float2(0, 0), make_float2(c, s) };
}
#define RSQ2 0.70710678118654752f
__device__ __forceinline__ M2 mH() {
    return { make_float2(RSQ2, 0), make_float2(RSQ2, 0), make_float2(RSQ2, 0), make_float2(-RSQ2, 0) };
}
__device__ __forceinline__ M2 mW() {   // W = H*S; W† Z W = -Y => YY = W†⊗W† ZZ W⊗W
    return { make_float2(RSQ2, 0), make_float2(0, RSQ2), make_float2(RSQ2, 0), make_float2(0, -RSQ2) };
}
__device__ __forceinline__ M2 mWd() {
    return { make_float2(RSQ2, 0), make_float2(RSQ2, 0), make_float2(0, -RSQ2), make_float2(0, RSQ2) };
}

// ================= layouts =================
// tid = wv*64 + l.  Layout Li: register-local j = qubits {3Li..3Li+2}
// L0: k = j | l<<3 | wv<<9          L1: k = (l&7) | j<<3 | (l>>3)<<6 | wv<<9
// L2: k = l | j<<6 | wv<<9          L3: k = l | wv<<6 | j<<9

template<int Li>
__device__ __forceinline__ int kOf(int t, int j) {
    const int mlo = (1 << (3 * Li)) - 1;
    return (t & mlo) | (j << (3 * Li)) | ((t & ~mlo) << 3);
}
__device__ __forceinline__ int slot0(int k) {
    int j = k & 7, t = k >> 3;
    return j * 512 + (t ^ j);
}

// ---- intra-wave trips (wave-private 512-v2f region wb, NO barrier) ----
template<int TYPE>   // TYPE 0: <0,1>/<1,0>   TYPE 1: <1,2>/<2,1>
__device__ __forceinline__ void itrip(v2f* amp, int l, v2f* wb) {
#pragma unroll
    for (int j = 0; j < 8; ++j) wb[j * 64 + (l ^ ((9 * j) & 63))] = amp[j];
    asm volatile("" ::: "memory");   // compiler fence; DS pipe is in-order per wave
#pragma unroll
    for (int j = 0; j < 8; ++j) {
        int jo, lo;
        if (TYPE == 0) { jo = l & 7;        lo = j | (l & 56); }
        else           { jo = (l >> 3) & 7; lo = (l & 7) | (j << 3); }
        amp[j] = wb[jo * 64 + (lo ^ ((9 * jo) & 63))];
    }
}

// ---- barrier trip <2,3> / <3,2> (involution: same formula both ways) ----
__device__ __forceinline__ void btrip(v2f* amp, int tid, int l, int wv, v2f* b) {
#pragma unroll
    for (int j = 0; j < 8; ++j) b[j * 512 + (tid ^ j)] = amp[j];
    __syncthreads();
#pragma unroll
    for (int j = 0; j < 8; ++j) amp[j] = b[wv * 512 + ((j * 64 + l) ^ wv)];
}

// ---- gate-matrix trio: 12 v2f in registers, loaded via 6x ds_read_b128 ----
struct Trio { v2f m[12]; };
__device__ __forceinline__ Trio load_trio(const float4 (*g4)[2]) {
    Trio t;
#pragma unroll
    for (int k = 0; k < 3; ++k) {
        float4 a = g4[k][0], b = g4[k][1];
        t.m[k * 4 + 0] = mkv(a.x, a.y); t.m[k * 4 + 1] = mkv(a.z, a.w);
        t.m[k * 4 + 2] = mkv(b.x, b.y); t.m[k * 4 + 3] = mkv(b.z, b.w);
    }
    return t;
}

template<int JB>
__device__ __forceinline__ void g1_reg(v2f* amp, const v2f* g) {
    const int m = 1 << JB;
    v2f m00 = g[0], m01 = g[1], m10 = g[2], m11 = g[3];
#pragma unroll
    for (int j = 0; j < 8; ++j)
        if (!(j & m)) {
            v2f a = amp[j], b = amp[j | m];
            amp[j]     = cfma(m01, b, cmulp(m00, a));
            amp[j | m] = cfma(m11, b, cmulp(m10, a));
        }
}
__device__ __forceinline__ void apply_trio(v2f* amp, const Trio& t) {
    g1_reg<0>(amp, t.m + 0);  g1_reg<1>(amp, t.m + 4);  g1_reg<2>(amp, t.m + 8);
}

// ---- fused diagonal Ising phase (all 12 ring edges) in L3: k = tid(0-8) | j<<9 ----
__device__ __forceinline__ void diag_L3(v2f* amp, const float* zh, int tid) {
    float phi0 = 0.f;
#pragma unroll
    for (int e = 3; e <= 10; ++e) {   // edges entirely in tid bits: thread-constant
        int hi = 11 - e, lo = 10 - e;
        phi0 += (((tid >> hi) ^ (tid >> lo)) & 1) ? zh[e] : -zh[e];
    }
    float z0 = zh[0], z1 = zh[1], z2 = zh[2], z11 = zh[11];
    int t8 = (tid >> 8) & 1, t0 = tid & 1;
#pragma unroll
    for (int j = 0; j < 8; ++j) {
        int j0 = j & 1, j1 = (j >> 1) & 1, j2 = (j >> 2) & 1;
        float phi = phi0
            + ((j2 ^ j1) ? z0 : -z0)       // (11,10)
            + ((j1 ^ j0) ? z1 : -z1)       // (10,9)
            + ((j0 ^ t8) ? z2 : -z2)       // (9,8)
            + ((j2 ^ t0) ? z11 : -z11);    // (11,0)
        float sp, cp;
        __sincosf(phi, &sp, &cp);
        amp[j] = cmulp(mkv(cp, sp), amp[j]);
    }
}

// ---- composed CNOT-ring source index ----
__device__ __forceinline__ int cnot_src(int k) {
#pragma unroll
    for (int e = 11; e >= 0; --e) {
        int hi = (e < 11) ? 11 - e : 11, lo = (e < 11) ? 10 - e : 0;
        if ((k >> hi) & 1) k ^= (1 << lo);
    }
    return k;
}

// ---- CNOT trip with PAIRWISE wave sync (no full barrier) ----
// Source-wave bits of the composed permutation: (w0^w1, w1^w2, w2) — each wave
// reads from exactly one producer wave, so an LDS flag handshake suffices.
// Per-wave DS ordering guarantees the flag store lands after the amp stores.
__device__ __forceinline__ void cnot_pair(v2f* amp, int tid, int l, int pw, int gen,
                                          const int* kslot, v2f* b,
                                          volatile unsigned* wflag, int wv) {
#pragma unroll
    for (int j = 0; j < 8; ++j) b[j * 512 + (tid ^ j)] = amp[j];
    asm volatile("" ::: "memory");
    __threadfence_block();                         // drain this wave's LDS writes
    if (l == 0) wflag[wv] = (unsigned)gen;
    asm volatile("" ::: "memory");
    int guard = 0;
    while (wflag[pw] < (unsigned)gen && guard < (1 << 26)) {
        ++guard;
        __builtin_amdgcn_s_sleep(1);
    }
    asm volatile("" ::: "memory");
#pragma unroll
    for (int j = 0; j < 8; ++j) amp[j] = b[kslot[j]];   // lands in L0
}

__global__ __launch_bounds__(NT) void qsim_kernel(
    const float* __restrict__ data,       // [64,12]
    const float* __restrict__ enc_scale,  // [12,3]
    const float* __restrict__ enc_bias,   // [12,3]
    const float* __restrict__ eta,        // [1,3]
    const float* __restrict__ ew_zz,      // [1,12]
    const float* __restrict__ ew_xx,      // [1,12]
    const float* __restrict__ ew_yy,      // [1,12]
    const float* __restrict__ nb_z,       // [1,12]
    const float* __restrict__ nb_x,       // [1,12]
    const float* __restrict__ nb_y,       // [1,12]
    const float* __restrict__ trots,      // [1,3,12,3]
    float* __restrict__ out)              // [64,12]
{
    __shared__ v2f bbuf[2][QDIM];     // 64 KB barrier double buffer
    __shared__ v2f ibuf[QDIM];        // 32 KB intra-wave buffer (512 v2f per wave)
    __shared__ float4 g1q4[72][2];    // fused 1q matrices, 32 B each
    __shared__ float zhalf[3][12];
    __shared__ float red[8][12];
    __shared__ unsigned wflag[8];     // pairwise wave-sync flags

    const int tid = threadIdx.x;
    const int l = tid & 63, wv = tid >> 6;
    const int bat = blockIdx.x;
    v2f* wb = &ibuf[wv * 512];

    // ---- fused gate tables (Ising basis changes folded into neighbors) ----
    if (tid < 36) {                      // encoding: b = tid/12, q = tid%12
        int b = tid / 12, q = tid % 12;
        float x  = data[bat * 12 + q];
        float ax = enc_scale[q * 3 + 0] * x + enc_bias[q * 3 + 0];
        float ay = enc_scale[q * 3 + 1] * x + enc_bias[q * 3 + 1];
        float az = enc_scale[q * 3 + 2] * x + enc_bias[q * 3 + 2];
        M2 M;
        if (b == 0)      M = mmul(mrz(az), mmul(mry(ay), mrx(ax)));   // ZZ: no basis change
        else if (b == 1) M = mmul(mH(), mmul(mry(ay), mrx(ax)));      // XX: H after enc
        else             M = mmul(mW(), mmul(mrz(az), mry(ay)));      // YY: W after enc
        g1q4[tid][0] = make_float4(M.a.x, M.a.y, M.b.x, M.b.y);
        g1q4[tid][1] = make_float4(M.c.x, M.c.y, M.d.x, M.d.y);
    } else if (tid < 72) {               // bias + trainables (+ closing basis change first)
        int i = tid - 36, b = i / 12, q = i % 12;
        float nb = (b == 0) ? nb_z[q] : (b == 1) ? nb_x[q] : nb_y[q];
        M2 M0 = (b == 0) ? mrz(nb) : (b == 1) ? mrx(nb) : mry(nb);
        float t0 = trots[(b * 12 + q) * 3 + 0];
        float t1 = trots[(b * 12 + q) * 3 + 1];
        float t2 = trots[(b * 12 + q) * 3 + 2];
        M2 M = mmul(mrz(t2), mmul(mry(t1), mmul(mrx(t0), M0)));
        if (b == 1)      M = mmul(M, mH());
        else if (b == 2) M = mmul(M, mWd());
        g1q4[tid][0] = make_float4(M.a.x, M.a.y, M.b.x, M.b.y);
        g1q4[tid][1] = make_float4(M.c.x, M.c.y, M.d.x, M.d.y);
    } else if (tid < 108) {              // diagonal half-angles per block/edge
        int i = tid - 72, b = i / 12, e = i % 12;
        const float* ew = (b == 0) ? ew_zz : (b == 1) ? ew_xx : ew_yy;
        zhalf[b][e] = 0.5f * eta[b] * ew[e];
    }
    if (tid < 8) wflag[tid] = 0u;
    __syncthreads();

    // pairwise CNOT partner wave: source wave = (w0^w1, w1^w2, w2)
    const int w0 = wv & 1, w1 = (wv >> 1) & 1, w2 = (wv >> 2) & 1;
    const int pw = (w0 ^ w1) | ((w1 ^ w2) << 1) | (w2 << 2);

    // precompute CNOT-ring gather slots (same permutation every block)
    int kslot[8];
#pragma unroll
    for (int j = 0; j < 8; ++j)
        kslot[j] = slot0(cnot_src(kOf<0>(tid, j)));

    v2f amp[8];
    int sel = 0;
#define NB (&bbuf[(sel ^= 1) ^ 1][0])

    for (int blk = 0; blk < 3; ++blk) {
        const float4(*Ge)[2] = &g1q4[blk * 12];
        const float4(*Gb)[2] = &g1q4[36 + blk * 12];

        if (blk == 0) {
            // ---- product-state shortcut: 12 enc gates on |0..0> == product state,
            //      synthesized directly in L3 (k = tid | j<<9). Saves the whole ladder.
            v2f base = mkv(1.f, 0.f);
#pragma unroll
            for (int q = 0; q < 9; ++q) {
                float4 r0 = Ge[q][0], r1 = Ge[q][1];
                v2f f = ((tid >> q) & 1) ? mkv(r1.x, r1.y) : mkv(r0.x, r0.y);
                base = cmulp(base, f);
            }
            v2f f9[2], f10[2], f11[2];
            { float4 r0 = Ge[9][0],  r1 = Ge[9][1];  f9[0]  = mkv(r0.x, r0.y); f9[1]  = mkv(r1.x, r1.y); }
            { float4 r0 = Ge[10][0], r1 = Ge[10][1]; f10[0] = mkv(r0.x, r0.y); f10[1] = mkv(r1.x, r1.y); }
            { float4 r0 = Ge[11][0], r1 = Ge[11][1]; f11[0] = mkv(r0.x, r0.y); f11[1] = mkv(r1.x, r1.y); }
#pragma unroll
            for (int j = 0; j < 8; ++j) {
                v2f t = cmulp(f9[j & 1], f10[(j >> 1) & 1]);
                t = cmulp(t, f11[(j >> 2) & 1]);
                amp[j] = cmulp(t, base);
            }
        } else {
            // ---- encoding ladder: L0 -> L1 -> L2 -> L3 ----
            Trio tA = load_trio(Ge + 0);
            apply_trio(amp, tA);
            itrip<0>(amp, l, wb);
            tA = load_trio(Ge + 3);
            apply_trio(amp, tA);
            itrip<1>(amp, l, wb);
            tA = load_trio(Ge + 6);
            apply_trio(amp, tA);
            btrip(amp, tid, l, wv, NB);
            tA = load_trio(Ge + 9);
            apply_trio(amp, tA);
        }

        // ---- Ising block == fused diagonal in the rotated basis (L3) ----
        diag_L3(amp, zhalf[blk], tid);

        // ---- bias + trots: L3 -> L2 -> L1 -> L0 ----
        Trio tB = load_trio(Gb + 9);
        apply_trio(amp, tB);
        btrip(amp, tid, l, wv, NB);
        tB = load_trio(Gb + 6);
        apply_trio(amp, tB);
        itrip<1>(amp, l, wb);
        tB = load_trio(Gb + 3);
        apply_trio(amp, tB);
        itrip<0>(amp, l, wb);
        tB = load_trio(Gb + 0);
        apply_trio(amp, tB);

        // ---- CNOT entangling ring: pairwise-synced permutation trip ----
        cnot_pair(amp, tid, l, pw, blk + 1, kslot, NB, wflag, wv);
    }

    // ---- Pauli-Z expectations (state in L0: k = (tid<<3)|j) ----
    float pr[8];
#pragma unroll
    for (int j = 0; j < 8; ++j) pr[j] = amp[j].x * amp[j].x + amp[j].y * amp[j].y;
    float psum = 0.f;
#pragma unroll
    for (int j = 0; j < 8; ++j) psum += pr[j];

    float acc[12];
#pragma unroll
    for (int i = 0; i < 9; ++i)
        acc[i] = ((tid >> (8 - i)) & 1) ? -psum : psum;
#pragma unroll
    for (int i = 9; i < 12; ++i) {
        float s = 0.f;
        int bit = 11 - i;  // j-bit index
#pragma unroll
        for (int j = 0; j < 8; ++j)
            s += ((j >> bit) & 1) ? -pr[j] : pr[j];
        acc[i] = s;
    }
#pragma unroll
    for (int off = 32; off > 0; off >>= 1)
#pragma unroll
        for (int i = 0; i < 12; ++i)
            acc[i] += __shfl_down(acc[i], off, 64);
    if (l == 0)
#pragma unroll
        for (int i = 0; i < 12; ++i) red[wv][i] = acc[i];
    __syncthreads();
    if (tid < 12) {
        float s = 0.f;
#pragma unroll
        for (int ww = 0; ww < 8; ++ww) s += red[ww][tid];
        out[bat * 12 + tid] = s;
    }
}

extern "C" void kernel_launch(void* const* d_in, const int* in_sizes, int n_in,
                              void* d_out, int out_size, void* d_ws, size_t ws_size,
                              hipStream_t stream) {
    const float* data      = (const float*)d_in[0];
    const float* enc_scale = (const float*)d_in[1];
    const float* enc_bias  = (const float*)d_in[2];
    const float* eta       = (const float*)d_in[3];
    const float* ew_zz     = (const float*)d_in[4];
    const float* ew_xx     = (const float*)d_in[5];
    const float* ew_yy     = (const float*)d_in[6];
    const float* nb_z      = (const float*)d_in[7];
    const float* nb_x      = (const float*)d_in[8];
    const float* nb_y      = (const float*)d_in[9];
    const float* trots     = (const float*)d_in[10];
    float* out = (float*)d_out;

    int batch = out_size / 12;  // 64
    qsim_kernel<<<batch, NT, 0, stream>>>(data, enc_scale, enc_bias, eta,
                                          ew_zz, ew_xx, ew_yy,
                                          nb_z, nb_x, nb_y, trots, out);
}